// Round 1
// baseline (1006.269 us; speedup 1.0000x reference)
//
#include <hip/hip_runtime.h>
#include <stdint.h>

#define NN 100000
#define NE 400000

typedef __attribute__((ext_vector_type(8))) short bf16x8;
typedef __attribute__((ext_vector_type(4))) float f32x4;

#define MFMA(a,b,c) __builtin_amdgcn_mfma_f32_16x16x32_bf16(a,b,c,0,0,0)

__device__ __forceinline__ unsigned short f2b(float f){
  union{float f;unsigned u;}v; v.f=f;
  return (unsigned short)((v.u + 0x7fffu + ((v.u>>16)&1u))>>16);
}
__device__ __forceinline__ float b2f(unsigned short s){
  union{unsigned u;float f;}v; v.u=((unsigned)s)<<16; return v.f;
}

// Wt[512][32] bf16: rows 0..127 = W_edge^T (for n_input); rows 128..511 = (W_edge@W_ih^T)^T (for gi recompute)
__global__ void k_wt(const float* __restrict__ W_edge, const float* __restrict__ W_ih,
                     unsigned short* __restrict__ Wt){
  int j = blockIdx.x;          // 0..511
  int k = threadIdx.x;         // 64 threads, use k<32
  if (k >= 32) return;
  float v;
  if (j < 128) {
    v = W_edge[k*128 + j];
  } else {
    const float* wi = W_ih + (size_t)(j-128)*128;
    const float* we = W_edge + (size_t)k*128;
    float s = 0.f;
    for (int d=0; d<128; ++d) s += we[d]*wi[d];
    v = s;
  }
  Wt[j*32 + k] = f2b(v);
}

// bf16 conversions: W_hh [384][128] straight; W_ro -> WroT [256][256] transposed; emb straight
__global__ void k_conv(const float* __restrict__ W_hh, const float* __restrict__ W_ro,
                       const float* __restrict__ emb,
                       unsigned short* __restrict__ Whh, unsigned short* __restrict__ WroT,
                       unsigned short* __restrict__ embB){
  int idx = blockIdx.x*256 + threadIdx.x;
  if (idx < 49152) { Whh[idx] = f2b(W_hh[idx]); return; }
  idx -= 49152;
  if (idx < 65536) { int h = idx>>8, k = idx&255; WroT[idx] = f2b(W_ro[k*256 + h]); return; }
  idx -= 65536;
  if (idx < 25600) { embB[idx] = f2b(emb[idx]); }
}

// f_edges fp32 [E][32] -> bf16
__global__ void k_fedges(const float* __restrict__ fe, unsigned short* __restrict__ feb){
  int i = blockIdx.x*256 + threadIdx.x;   // < 3,200,000 float4 chunks
  float4 v = ((const float4*)fe)[i];
  ushort4 o;
  o.x = f2b(v.x); o.y = f2b(v.y); o.z = f2b(v.z); o.w = f2b(v.w);
  ((ushort4*)feb)[i] = o;
}

// message_0 = n_input = f_edges @ W_edge  (row 0 zeroed), bf16 out
__global__ __launch_bounds__(256,2) void k_init(
    const unsigned short* __restrict__ feb,
    const unsigned short* __restrict__ Wt,
    unsigned short* __restrict__ m0)
{
  const int eb = blockIdx.x*64;
  const int tid = threadIdx.x;
  const int lane = tid & 63, wv = tid >> 6;
  const int jb = wv*32, lr = lane & 15, lk = lane >> 4;
  const f32x4 vzero = {0.f,0.f,0.f,0.f};
  f32x4 acc[4][2];
  #pragma unroll
  for (int m=0;m<4;++m){ acc[m][0]=vzero; acc[m][1]=vzero; }
  bf16x8 a[4];
  #pragma unroll
  for (int m=0;m<4;++m)
    a[m] = *(const bf16x8*)(feb + (size_t)(eb + m*16 + lr)*32 + lk*8);
  #pragma unroll
  for (int jf=0;jf<2;++jf){
    int jc = jb + jf*16 + lr;
    bf16x8 b = *(const bf16x8*)(Wt + jc*32 + lk*8);
    #pragma unroll
    for (int m=0;m<4;++m) acc[m][jf] = MFMA(a[m], b, acc[m][jf]);
  }
  #pragma unroll
  for (int jf=0;jf<2;++jf){
    int j = jb + jf*16 + lr;
    #pragma unroll
    for (int m=0;m<4;++m){
      #pragma unroll
      for (int rg=0;rg<4;++rg){
        int e = eb + m*16 + lk*4 + rg;
        m0[(size_t)e*128 + j] = (e==0) ? (unsigned short)0 : f2b(acc[m][jf][rg]);
      }
    }
  }
}

// a_msg[n] = sum_k msg[node2edge[n][k]]
__global__ __launch_bounds__(256,4) void k_agg(
    const unsigned short* __restrict__ msg,
    const int* __restrict__ n2e,
    unsigned short* __restrict__ amsg)
{
  int t = blockIdx.x*256 + threadIdx.x;
  int node = t >> 4, q = t & 15;
  const int* ip = n2e + (size_t)node*6;
  float acc[8] = {0,0,0,0,0,0,0,0};
  #pragma unroll
  for (int k=0;k<6;++k){
    int e = ip[k];
    union{uint4 u; unsigned short s[8];} v;
    v.u = *(const uint4*)(msg + (size_t)e*128 + q*8);
    #pragma unroll
    for (int j=0;j<8;++j) acc[j] += b2f(v.s[j]);
  }
  union{uint4 u; unsigned short s[8];} o;
  #pragma unroll
  for (int j=0;j<8;++j) o.s[j] = f2b(acc[j]);
  *(uint4*)(amsg + (size_t)node*128 + q*8) = o.u;
}

// fused: h = amsg[edge2node] - msg[b2revb]; gates = gi(recomputed) + h@W_hh^T; msg_out = GRU
__global__ __launch_bounds__(256,2) void k_step(
    const unsigned short* __restrict__ msg,
    const unsigned short* __restrict__ amsg,
    const unsigned short* __restrict__ feb,
    const unsigned short* __restrict__ Wt,
    const unsigned short* __restrict__ Whh,
    const int* __restrict__ edge2node,
    const int* __restrict__ b2revb,
    const float* __restrict__ bih,
    const float* __restrict__ bhh,
    unsigned short* __restrict__ mout)
{
  __shared__ __align__(16) unsigned short hl[64*128];   // h tile, XOR-swizzled
  const int eb = blockIdx.x*64;
  const int tid = threadIdx.x;

  // build h tile: 64 rows x 16 chunks(16B)
  #pragma unroll
  for (int i=0;i<4;++i){
    int idx = tid + 256*i;
    int row = idx >> 4, q = idx & 15;
    int e = eb + row;
    int sn = edge2node[e];
    int sb = b2revb[e];
    union{uint4 u; unsigned short s[8];} va, vb, vo;
    va.u = *(const uint4*)(amsg + (size_t)sn*128 + q*8);
    vb.u = *(const uint4*)(msg  + (size_t)sb*128 + q*8);
    #pragma unroll
    for (int j=0;j<8;++j) vo.s[j] = f2b(b2f(va.s[j]) - b2f(vb.s[j]));
    *(uint4*)(hl + row*128 + ((q ^ (row&7))*8)) = vo.u;
  }
  __syncthreads();

  const int lane = tid & 63;
  const int wv = tid >> 6;
  const int jb = wv*32;
  const int lr = lane & 15;
  const int lk = lane >> 4;

  const f32x4 vzero = {0.f,0.f,0.f,0.f};
  f32x4 r_acc[4][2], z_acc[4][2], gin[4][2], ghn[4][2];
  #pragma unroll
  for (int m=0;m<4;++m){
    #pragma unroll
    for (int jf=0;jf<2;++jf){
      r_acc[m][jf]=vzero; z_acc[m][jf]=vzero; gin[m][jf]=vzero; ghn[m][jf]=vzero;
    }
  }

  // gi phase (K=32): A = f_edges bf16, B = Wce^T rows of Wt
  {
    bf16x8 a[4];
    #pragma unroll
    for (int m=0;m<4;++m)
      a[m] = *(const bf16x8*)(feb + (size_t)(eb + m*16 + lr)*32 + lk*8);
    #pragma unroll
    for (int jf=0;jf<2;++jf){
      int jc = jb + jf*16 + lr;
      bf16x8 br = *(const bf16x8*)(Wt + (128+jc)*32 + lk*8);
      bf16x8 bz = *(const bf16x8*)(Wt + (256+jc)*32 + lk*8);
      bf16x8 bn = *(const bf16x8*)(Wt + (384+jc)*32 + lk*8);
      #pragma unroll
      for (int m=0;m<4;++m){
        r_acc[m][jf] = MFMA(a[m], br, r_acc[m][jf]);
        z_acc[m][jf] = MFMA(a[m], bz, z_acc[m][jf]);
        gin[m][jf]   = MFMA(a[m], bn, gin[m][jf]);
      }
    }
  }

  // gh phase (K=128 over h tile)
  #pragma unroll
  for (int kk=0;kk<4;++kk){
    bf16x8 a[4];
    #pragma unroll
    for (int m=0;m<4;++m){
      int row = m*16 + lr;
      a[m] = *(const bf16x8*)(hl + row*128 + (((kk*4+lk) ^ (row&7))*8));
    }
    #pragma unroll
    for (int jf=0;jf<2;++jf){
      int jc = jb + jf*16 + lr;
      bf16x8 br = *(const bf16x8*)(Whh + (size_t)jc*128       + kk*32 + lk*8);
      bf16x8 bz = *(const bf16x8*)(Whh + (size_t)(128+jc)*128 + kk*32 + lk*8);
      bf16x8 bn = *(const bf16x8*)(Whh + (size_t)(256+jc)*128 + kk*32 + lk*8);
      #pragma unroll
      for (int m=0;m<4;++m){
        r_acc[m][jf] = MFMA(a[m], br, r_acc[m][jf]);
        z_acc[m][jf] = MFMA(a[m], bz, z_acc[m][jf]);
        ghn[m][jf]   = MFMA(a[m], bn, ghn[m][jf]);
      }
    }
  }

  // epilogue: gates + write message
  #pragma unroll
  for (int jf=0;jf<2;++jf){
    int j = jb + jf*16 + lr;
    float br_ = bih[j]     + bhh[j];
    float bz_ = bih[128+j] + bhh[128+j];
    float bni = bih[256+j];
    float bnh = bhh[256+j];
    #pragma unroll
    for (int m=0;m<4;++m){
      #pragma unroll
      for (int rg=0;rg<4;++rg){
        int row = m*16 + lk*4 + rg;
        int e = eb + row;
        float rv = 1.f/(1.f + __expf(-(r_acc[m][jf][rg] + br_)));
        float zv = 1.f/(1.f + __expf(-(z_acc[m][jf][rg] + bz_)));
        float na = gin[m][jf][rg] + bni + rv*(ghn[m][jf][rg] + bnh);
        float nv = 2.f/(1.f + __expf(-2.f*na)) - 1.f;
        float hv = b2f(hl[row*128 + (((j>>3) ^ (row&7))*8) + (j&7)]);
        float mv = (1.f - zv)*nv + zv*hv;
        mout[(size_t)e*128 + j] = (e==0) ? (unsigned short)0 : f2b(mv);
      }
    }
  }
}

// out = relu(concat(emb[f_nodes], a_msg) @ W_ro + b_ro), fp32 out
__global__ __launch_bounds__(256,2) void k_readout(
    const unsigned short* __restrict__ amsg,
    const unsigned short* __restrict__ embB,
    const int* __restrict__ f_nodes,
    const unsigned short* __restrict__ WroT,
    const float* __restrict__ b_ro,
    float* __restrict__ out)
{
  __shared__ __align__(16) unsigned short al[64*256];   // A tile [64 nodes][256 k], swizzled
  const int nb = blockIdx.x*64;
  const int tid = threadIdx.x;
  #pragma unroll
  for (int i=0;i<8;++i){
    int idx = tid + 256*i;           // 0..2047: 64 rows x 32 chunks
    int row = idx >> 5, q = idx & 31;
    int node = nb + row; if (node >= NN) node = NN-1;
    const unsigned short* src = (q < 16)
        ? (embB + (size_t)f_nodes[node]*128 + q*8)
        : (amsg + (size_t)node*128 + (q-16)*8);
    uint4 v = *(const uint4*)src;
    *(uint4*)(al + row*256 + ((q ^ (row&7))*8)) = v;
  }
  __syncthreads();

  const int lane = tid & 63, wv = tid >> 6;
  const int hb = wv*64, lr = lane & 15, lk = lane >> 4;
  const f32x4 vzero = {0.f,0.f,0.f,0.f};
  f32x4 acc[4][4];
  #pragma unroll
  for (int m=0;m<4;++m){
    #pragma unroll
    for (int jf=0;jf<4;++jf) acc[m][jf]=vzero;
  }

  #pragma unroll
  for (int kk=0;kk<8;++kk){
    bf16x8 a[4];
    #pragma unroll
    for (int m=0;m<4;++m){
      int row = m*16 + lr;
      a[m] = *(const bf16x8*)(al + row*256 + (((kk*4+lk) ^ (row&7))*8));
    }
    #pragma unroll
    for (int jf=0;jf<4;++jf){
      int hc = hb + jf*16 + lr;
      bf16x8 b = *(const bf16x8*)(WroT + (size_t)hc*256 + kk*32 + lk*8);
      #pragma unroll
      for (int m=0;m<4;++m) acc[m][jf] = MFMA(a[m], b, acc[m][jf]);
    }
  }

  #pragma unroll
  for (int jf=0;jf<4;++jf){
    int hc = hb + jf*16 + lr;
    float bb = b_ro[hc];
    #pragma unroll
    for (int m=0;m<4;++m){
      #pragma unroll
      for (int rg=0;rg<4;++rg){
        int node = nb + m*16 + lk*4 + rg;
        if (node < NN) out[(size_t)node*256 + hc] = fmaxf(acc[m][jf][rg] + bb, 0.f);
      }
    }
  }
}

extern "C" void kernel_launch(void* const* d_in, const int* in_sizes, int n_in,
                              void* d_out, int out_size, void* d_ws, size_t ws_size,
                              hipStream_t stream) {
  const int*   f_nodes   = (const int*)d_in[0];
  const float* f_edges   = (const float*)d_in[1];
  const int*   node2edge = (const int*)d_in[2];
  const int*   edge2node = (const int*)d_in[3];
  const int*   b2revb    = (const int*)d_in[4];
  const float* emb       = (const float*)d_in[5];
  const float* W_edge    = (const float*)d_in[6];
  const float* W_ih      = (const float*)d_in[7];
  const float* W_hh      = (const float*)d_in[8];
  const float* b_ih      = (const float*)d_in[9];
  const float* b_hh      = (const float*)d_in[10];
  const float* W_ro      = (const float*)d_in[11];
  const float* b_ro      = (const float*)d_in[12];
  float* out = (float*)d_out;

  char* ws = (char*)d_ws;
  unsigned short* msgA = (unsigned short*)ws; ws += (size_t)NE*128*2;
  unsigned short* msgB = (unsigned short*)ws; ws += (size_t)NE*128*2;
  unsigned short* amsg = (unsigned short*)ws; ws += (size_t)NN*128*2;
  unsigned short* feb  = (unsigned short*)ws; ws += (size_t)NE*32*2;
  unsigned short* Wt   = (unsigned short*)ws; ws += 512*32*2;
  unsigned short* Whh  = (unsigned short*)ws; ws += 384*128*2;
  unsigned short* WroT = (unsigned short*)ws; ws += 256*256*2;
  unsigned short* embB = (unsigned short*)ws; ws += 200*128*2;

  k_wt<<<512, 64, 0, stream>>>(W_edge, W_ih, Wt);
  k_conv<<<549, 256, 0, stream>>>(W_hh, W_ro, emb, Whh, WroT, embB);
  k_fedges<<<12500, 256, 0, stream>>>(f_edges, feb);
  k_init<<<6250, 256, 0, stream>>>(feb, Wt, msgA);

  unsigned short* cur = msgA;
  unsigned short* nxt = msgB;
  for (int s = 0; s < 4; ++s) {
    k_agg<<<6250, 256, 0, stream>>>(cur, node2edge, amsg);
    k_step<<<6250, 256, 0, stream>>>(cur, amsg, feb, Wt, Whh,
                                     edge2node, b2revb, b_ih, b_hh, nxt);
    unsigned short* t = cur; cur = nxt; nxt = t;
  }
  k_agg<<<6250, 256, 0, stream>>>(cur, node2edge, amsg);
  k_readout<<<1563, 256, 0, stream>>>(amsg, embB, f_nodes, WroT, b_ro, out);
}